// Round 1
// baseline (369.611 us; speedup 1.0000x reference)
//
#include <hip/hip_runtime.h>
#include <math.h>

#define BIG_NEG -1.0e9f

// Problem constants (fixed by setup_inputs)
constexpr int B  = 4;
constexpr int N1 = 511;
constexpr int D  = 64;
constexpr int C1 = 31;
constexpr int K  = 32;
constexpr int N  = N1 + 1;        // 512
constexpr int C  = C1 + 1;        // 32
constexpr int CSLEN = N + K + 1;  // 545

// Workspace layout (float offsets)
constexpr int WS_TRANS = 0;                    // [32][32]
constexpr int WS_INIT  = 1024;                 // [32]
constexpr int WS_LEN   = 1056;                 // [32][32]  (K x C)
constexpr int WS_P     = 2080;                 // [64][64]  precision matrix
constexpr int WS_W     = 6176;                 // [64][32]  w transposed: wT[dd][c]
constexpr int WS_BIAS  = 8224;                 // [32]
constexpr int WS_EMIS  = 8256;                 // [B][N][C] = 65536
constexpr int WS_CS    = WS_EMIS + B * N * C;  // 73792: [B][CSLEN][C] = 69760
// total 143552 floats = 574 KB

// ---------------------------------------------------------------------------
// Small tables: trans_a (masked-diag log_softmax over axis 0), init_a,
// Poisson length_a, and the EOS emission row.
// ---------------------------------------------------------------------------
__global__ __launch_bounds__(1024) void k_small(const float* __restrict__ tl,
                                                const float* __restrict__ il,
                                                const float* __restrict__ plr,
                                                float* __restrict__ ws) {
    const int tid = threadIdx.x;
    const int i = tid >> 5;   // 0..31
    const int j = tid & 31;   // 0..31

    // default trans_a: row 31 (EOS prev) = 0, everything else BIG_NEG
    ws[WS_TRANS + i * 32 + j] = (i == C1) ? 0.0f : BIG_NEG;

    // length_a[k=i][c=j]
    if (j < C1) {
        float lr = plr[j];
        ws[WS_LEN + i * 32 + j] =
            (float)i * lr - expf(lr) - lgammaf((float)i + 1.0f);
    } else {
        ws[WS_LEN + i * 32 + j] = (i == 1) ? 0.0f : BIG_NEG;
    }

    // EOS emission row: emis_a[b][N-1][c] = (c==31) ? 0 : BIG_NEG
    if (tid < B * C) {
        int bb = tid >> 5, cc = tid & 31;
        ws[WS_EMIS + (bb * N + N1) * C + cc] = (cc == C1) ? 0.0f : BIG_NEG;
    }

    __syncthreads();

    // trans columns: log_softmax over axis 0 with masked diagonal
    if (tid < C1) {
        const int jj = tid;
        float m = BIG_NEG;
        for (int ii = 0; ii < C1; ++ii) {
            float v = (ii == jj) ? BIG_NEG : tl[ii * C1 + jj];
            m = fmaxf(m, v);
        }
        float s = 0.0f;
        for (int ii = 0; ii < C1; ++ii) {
            float v = (ii == jj) ? BIG_NEG : tl[ii * C1 + jj];
            s += expf(v - m);
        }
        float lse = m + logf(s);
        for (int ii = 0; ii < C1; ++ii) {
            float v = (ii == jj) ? BIG_NEG : tl[ii * C1 + jj];
            ws[WS_TRANS + ii * 32 + jj] = v - lse;
        }
    }

    // init_a
    if (tid == 1023) {
        float m = -1.0e30f;
        for (int cc = 0; cc < C1; ++cc) m = fmaxf(m, il[cc]);
        float s = 0.0f;
        for (int cc = 0; cc < C1; ++cc) s += expf(il[cc] - m);
        float lse = m + logf(s);
        for (int cc = 0; cc < C1; ++cc) ws[WS_INIT + cc] = il[cc] - lse;
        ws[WS_INIT + C1] = BIG_NEG;
    }
}

// ---------------------------------------------------------------------------
// Cholesky of 64x64 cov, Linv, P = Linv^T Linv, w_c = P mu_c (transposed),
// bias_c = -0.5*(d*log(2pi) + logdet + mu_c^T P mu_c)
// ---------------------------------------------------------------------------
__global__ __launch_bounds__(1024) void k_chol(const float* __restrict__ cov,
                                               const float* __restrict__ means,
                                               float* __restrict__ ws) {
    __shared__ float A[64][64];   // cov -> L -> P
    __shared__ float Li[64][64];  // Linv, later reused to stash w rows
    __shared__ float s_logdet;
    const int tid = threadIdx.x;

    for (int idx = tid; idx < 64 * 64; idx += 1024)
        A[idx >> 6][idx & 63] = cov[idx];
    __syncthreads();

    // Cholesky (lower), column by column
    for (int j = 0; j < 64; ++j) {
        if (tid == j) {
            float s = A[j][j];
            for (int k2 = 0; k2 < j; ++k2) s -= A[j][k2] * A[j][k2];
            A[j][j] = sqrtf(s);
        }
        __syncthreads();
        if (tid > j && tid < 64) {
            float s = A[tid][j];
            for (int k2 = 0; k2 < j; ++k2) s -= A[tid][k2] * A[j][k2];
            A[tid][j] = s / A[j][j];
        }
        __syncthreads();
    }

    if (tid == 0) {
        float s = 0.0f;
        for (int ii = 0; ii < 64; ++ii) s += logf(A[ii][ii]);
        s_logdet = 2.0f * s;
    }

    // Linv: thread j computes column j (forward substitution); zero the upper.
    if (tid < 64) {
        const int j = tid;
        for (int ii = 0; ii < j; ++ii) Li[ii][j] = 0.0f;
        Li[j][j] = 1.0f / A[j][j];
        for (int ii = j + 1; ii < 64; ++ii) {
            float s = 0.0f;
            for (int k2 = j; k2 < ii; ++k2) s += A[ii][k2] * Li[k2][j];
            Li[ii][j] = -s / A[ii][ii];
        }
    }
    __syncthreads();

    // P = Li^T * Li  (symmetric).  thread -> (i, j0..j0+3)
    {
        const int i  = tid >> 4;
        const int j0 = (tid & 15) << 2;
        float a0 = 0, a1 = 0, a2 = 0, a3 = 0;
        for (int e = 0; e < 64; ++e) {
            float li = Li[e][i];
            a0 += li * Li[e][j0 + 0];
            a1 += li * Li[e][j0 + 1];
            a2 += li * Li[e][j0 + 2];
            a3 += li * Li[e][j0 + 3];
        }
        __syncthreads();  // everyone done reading A (chol) before overwrite
        A[i][j0 + 0] = a0;
        A[i][j0 + 1] = a1;
        A[i][j0 + 2] = a2;
        A[i][j0 + 3] = a3;
        float4 p4 = {a0, a1, a2, a3};
        *(float4*)&ws[WS_P + i * 64 + j0] = p4;
    }
    __syncthreads();

    // w_c[dd] = sum_e P[dd][e] * mu[c][e];  store transposed wT[dd][c].
    // thread -> (c = tid>>5, dd0 = (tid&31)*2); also stash into Li[c][dd].
    {
        const int c   = tid >> 5;
        const int dd0 = (tid & 31) << 1;
        if (c < C1) {
            float a0 = 0, a1 = 0;
            for (int e = 0; e < 64; ++e) {
                float m = means[c * 64 + e];
                a0 += A[dd0 + 0][e] * m;
                a1 += A[dd0 + 1][e] * m;
            }
            ws[WS_W + (dd0 + 0) * 32 + c] = a0;
            ws[WS_W + (dd0 + 1) * 32 + c] = a1;
            Li[c][dd0 + 0] = a0;
            Li[c][dd0 + 1] = a1;
        }
    }
    __syncthreads();

    // bias_c = -0.5 * (d*log(2pi) + logdet + q_c)
    if (tid < C1) {
        float q = 0.0f;
        for (int dd = 0; dd < 64; ++dd) q += means[tid * 64 + dd] * Li[tid][dd];
        const float c0 = 64.0f * 1.8378770664093453f + s_logdet;  // log(2*pi)
        ws[WS_BIAS + tid] = -0.5f * (c0 + q);
    }
}

// ---------------------------------------------------------------------------
// Emission log-probs: emis[b,n,c] = bias_c + w_c.x - 0.5 * x^T P x
// One wave per (b,n).
// ---------------------------------------------------------------------------
__global__ __launch_bounds__(64) void k_emis(const float* __restrict__ feat,
                                             float* __restrict__ ws) {
    const int bid = blockIdx.x;
    const int b = bid / N1, n = bid % N1;
    const int tid = threadIdx.x;
    __shared__ float xs[64];

    const float x = feat[(b * N1 + n) * 64 + tid];
    xs[tid] = x;
    __syncthreads();

    // z_tid = sum_dd P[dd][tid] * x[dd]   (P symmetric -> coalesced reads)
    const float* __restrict__ P = ws + WS_P;
    float z = 0.0f;
    for (int dd = 0; dd < 64; ++dd) z += P[dd * 64 + tid] * xs[dd];

    float xz = x * z;
    for (int m = 32; m >= 1; m >>= 1) xz += __shfl_xor(xz, m);

    float val = BIG_NEG;
    if (tid < C1) {
        float s = ws[WS_BIAS + tid] - 0.5f * xz;
        const float* __restrict__ wT = ws + WS_W;
        for (int dd = 0; dd < 64; ++dd) s += wT[dd * 32 + tid] * xs[dd];
        val = s;
    }
    if (tid < C) ws[WS_EMIS + (b * N + n) * C + tid] = val;
}

// ---------------------------------------------------------------------------
// Padded cumsum over time, per (b, c): cs[b][i][c] = sum_{t<i} emis_a[b][t][c]
// (emis rows >= N are zero padding).
// ---------------------------------------------------------------------------
__global__ __launch_bounds__(128) void k_cumsum(float* __restrict__ ws) {
    const int tid = threadIdx.x;
    const int b = tid >> 5, cc = tid & 31;
    const float* __restrict__ emis = ws + WS_EMIS + b * N * C;
    float* __restrict__ cs = ws + WS_CS + b * CSLEN * C;

    float acc = 0.0f;
    cs[cc] = 0.0f;
    for (int i2 = 1; i2 <= N; ++i2) {
        acc += emis[(i2 - 1) * C + cc];
        cs[i2 * C + cc] = acc;
    }
    for (int i2 = N + 1; i2 < CSLEN; ++i2) cs[i2 * C + cc] = acc;
}

// ---------------------------------------------------------------------------
// Main assembly: one block per (b,t); 256 threads; thread -> (cp, c0..c0+3);
// loop over k, fully-coalesced float4 stores.
// ---------------------------------------------------------------------------
__global__ __launch_bounds__(256) void k_main(const float* __restrict__ ws,
                                              float* __restrict__ out) {
    const int bid = blockIdx.x;
    const int b = bid / N1, t = bid % N1;
    const int tid = threadIdx.x;
    const int cp = tid >> 3;
    const int c0 = (tid & 7) << 2;

    __shared__ __align__(16) float slen[K * C];
    for (int idx = tid; idx < K * C; idx += 256) slen[idx] = ws[WS_LEN + idx];

    const float4 tr4 = *(const float4*)&ws[WS_TRANS + cp * 32 + c0];
    float4 in4 = {0.0f, 0.0f, 0.0f, 0.0f};
    if (t == 0) in4 = *(const float4*)&ws[WS_INIT + c0];

    const float* __restrict__ cs = ws + WS_CS + (b * CSLEN + t) * C;
    const float4 cst = *(const float4*)&cs[c0];

    // pre = trans + init - cs[t]
    float4 pre;
    pre.x = tr4.x + in4.x - cst.x;
    pre.y = tr4.y + in4.y - cst.y;
    pre.z = tr4.z + in4.z - cst.z;
    pre.w = tr4.w + in4.w - cst.w;

    const float emisN = (cp == C1) ? 0.0f : BIG_NEG;
    const int keos = N1 - t;  // matches k only when 1 <= keos <= 31

    const size_t obase = (size_t)bid * K * (C * C) + (size_t)(cp * 32 + c0);
    __syncthreads();

#pragma unroll 4
    for (int k = 0; k < K; ++k) {
        const float4 len4 = *(const float4*)&slen[k * 32 + c0];
        const float4 csk  = *(const float4*)&cs[k * C + c0];
        const float add = (k == keos) ? emisN : 0.0f;
        float4 o;
        o.x = pre.x + len4.x + csk.x + add;
        o.y = pre.y + len4.y + csk.y + add;
        o.z = pre.z + len4.z + csk.z + add;
        o.w = pre.w + len4.w + csk.w + add;
        *(float4*)&out[obase + (size_t)k * (C * C)] = o;
    }
}

// ---------------------------------------------------------------------------
extern "C" void kernel_launch(void* const* d_in, const int* in_sizes, int n_in,
                              void* d_out, int out_size, void* d_ws, size_t ws_size,
                              hipStream_t stream) {
    const float* feat = (const float*)d_in[0];
    const float* tl   = (const float*)d_in[1];
    const float* il   = (const float*)d_in[2];
    const float* plr  = (const float*)d_in[3];
    const float* gm   = (const float*)d_in[4];
    const float* gc   = (const float*)d_in[5];
    float* ws  = (float*)d_ws;
    float* out = (float*)d_out;

    hipLaunchKernelGGL(k_small, dim3(1), dim3(1024), 0, stream, tl, il, plr, ws);
    hipLaunchKernelGGL(k_chol, dim3(1), dim3(1024), 0, stream, gc, gm, ws);
    hipLaunchKernelGGL(k_emis, dim3(B * N1), dim3(64), 0, stream, feat, ws);
    hipLaunchKernelGGL(k_cumsum, dim3(1), dim3(128), 0, stream, ws);
    hipLaunchKernelGGL(k_main, dim3(B * N1), dim3(256), 0, stream, ws, out);
}

// Round 3
// 172.929 us; speedup vs baseline: 2.1374x; 2.1374x over previous
//
#include <hip/hip_runtime.h>
#include <math.h>

#define BIG_NEG -1.0e9f

// Problem constants (fixed by setup_inputs)
constexpr int B  = 4;
constexpr int N1 = 511;
constexpr int D  = 64;
constexpr int C1 = 31;
constexpr int K  = 32;
constexpr int N  = N1 + 1;        // 512
constexpr int C  = C1 + 1;        // 32
constexpr int CSLEN = N + K + 1;  // 545

// Workspace layout (float offsets)
constexpr int WS_TRANS = 0;                    // [32][32]
constexpr int WS_INIT  = 1024;                 // [32]
constexpr int WS_LEN   = 1056;                 // [32][32]  (K x C)
constexpr int WS_P     = 2080;                 // [64][64]  precision matrix
constexpr int WS_W     = 6176;                 // [64][32]  w transposed: wT[dd][c]
constexpr int WS_BIAS  = 8224;                 // [32]
constexpr int WS_EMIS  = 8256;                 // [B][N][C] = 65536
constexpr int WS_CS    = WS_EMIS + B * N * C;  // 73792: [B][CSLEN][C] = 69760

// ---------------------------------------------------------------------------
// Fused prep: small tables + Gauss-Jordan inversion of cov (fully parallel,
// 2 barriers per pivot step) + logdet from pivots + wT + bias.
// ---------------------------------------------------------------------------
__global__ __launch_bounds__(1024) void k_prep(const float* __restrict__ tl,
                                               const float* __restrict__ il,
                                               const float* __restrict__ plr,
                                               const float* __restrict__ cov,
                                               const float* __restrict__ means,
                                               float* __restrict__ ws) {
    __shared__ float M[64][128];   // augmented [cov | I]
    __shared__ float piv[64];
    __shared__ float rpiv[64];
    __shared__ float mu[C1][64];
    __shared__ float wsh[64][33];  // padded: bank = (dd+c)%32
    __shared__ float s_logdet;

    const int tid = threadIdx.x;
    const int ii = tid >> 4;       // row 0..63
    const int cg = tid & 15;       // col group; owns cols k = cg + 16*c2

    // ---- load augmented matrix (scattered cols -> <=4-way LDS conflict) ----
#pragma unroll
    for (int c2 = 0; c2 < 8; ++c2) {
        const int k = cg + 16 * c2;
        M[ii][k] = (k < 64) ? cov[ii * 64 + k] : ((k - 64 == ii) ? 1.0f : 0.0f);
    }
    // ---- load means into LDS (C1*64 = 1984 elements > 1024 threads!) ----
    for (int idx = tid; idx < C1 * 64; idx += 1024)
        mu[idx >> 6][idx & 63] = means[idx];

    // ---- small tables: defaults ----
    const int i = tid >> 5, j = tid & 31;
    ws[WS_TRANS + i * 32 + j] = (i == C1) ? 0.0f : BIG_NEG;
    if (j < C1) {
        float lr = plr[j];
        ws[WS_LEN + i * 32 + j] =
            (float)i * lr - expf(lr) - lgammaf((float)i + 1.0f);
    } else {
        ws[WS_LEN + i * 32 + j] = (i == 1) ? 0.0f : BIG_NEG;
    }
    if (tid < B * C) {
        int bb = tid >> 5, cc = tid & 31;
        ws[WS_EMIS + (bb * N + N1) * C + cc] = (cc == C1) ? 0.0f : BIG_NEG;
    }
    __syncthreads();

    // ---- trans columns: log_softmax over axis 0 with masked diagonal ----
    if (tid < C1) {
        const int jj = tid;
        float m = BIG_NEG;
        for (int r = 0; r < C1; ++r) {
            float v = (r == jj) ? BIG_NEG : tl[r * C1 + jj];
            m = fmaxf(m, v);
        }
        float s = 0.0f;
        for (int r = 0; r < C1; ++r) {
            float v = (r == jj) ? BIG_NEG : tl[r * C1 + jj];
            s += expf(v - m);
        }
        float lse = m + logf(s);
        for (int r = 0; r < C1; ++r) {
            float v = (r == jj) ? BIG_NEG : tl[r * C1 + jj];
            ws[WS_TRANS + r * 32 + jj] = v - lse;
        }
    }
    // ---- init_a ----
    if (tid == 1023) {
        float m = -1.0e30f;
        for (int cc = 0; cc < C1; ++cc) m = fmaxf(m, il[cc]);
        float s = 0.0f;
        for (int cc = 0; cc < C1; ++cc) s += expf(il[cc] - m);
        float lse = m + logf(s);
        for (int cc = 0; cc < C1; ++cc) ws[WS_INIT + cc] = il[cc] - lse;
        ws[WS_INIT + C1] = BIG_NEG;
    }

    // ---- Gauss-Jordan: 64 steps, 2 barriers each, fully parallel ----
    for (int jj = 0; jj < 64; ++jj) {
        const float p = M[jj][jj];          // broadcast
        const float f = M[ii][jj] / p;      // per-row factor
        if (tid == jj * 16) piv[jj] = p;    // thread (ii==jj, cg==0)
        __syncthreads();                    // all f reads done
        if (ii != jj) {
#pragma unroll
            for (int c2 = 0; c2 < 8; ++c2) {
                const int k = cg + 16 * c2;
                M[ii][k] -= f * M[jj][k];
            }
        }
        __syncthreads();                    // updates visible for next pivot
    }

    // ---- logdet + reciprocal pivots ----
    if (tid == 0) {
        float s = 0.0f;
        for (int r = 0; r < 64; ++r) s += logf(piv[r]);
        s_logdet = s;
    }
    if (tid < 64) rpiv[tid] = 1.0f / piv[tid];

    // ---- P = inv(cov) to global: P[r][k] = M[r][64+k] / piv[r] ----
    {
        const float rp = 1.0f / piv[ii];
#pragma unroll
        for (int c2 = 0; c2 < 8; ++c2) {
            const int k = cg + 16 * c2;
            if (k >= 64) ws[WS_P + ii * 64 + (k - 64)] = M[ii][k] * rp;
        }
    }
    __syncthreads();   // rpiv, s_logdet, mu ready

    // ---- wT[dd][c] = sum_e P[e][dd] * mu[c][e]   (P symmetric) ----
    {
        const int c = tid >> 5;
        const int l = tid & 31;
        if (c < C1) {
#pragma unroll
            for (int half = 0; half < 2; ++half) {
                const int dd = l + 32 * half;
                float a = 0.0f;
                for (int e = 0; e < 64; ++e)
                    a += M[e][64 + dd] * (mu[c][e] * rpiv[e]);
                ws[WS_W + dd * 32 + c] = a;
                wsh[dd][c] = a;
            }
        }
    }
    __syncthreads();

    // ---- bias_c = -0.5 * (d*log(2pi) + logdet + mu_c^T P mu_c) ----
    if (tid < C1) {
        float q = 0.0f;
        for (int dd = 0; dd < 64; ++dd) q += mu[tid][dd] * wsh[dd][tid];
        ws[WS_BIAS + tid] =
            -0.5f * (64.0f * 1.8378770664093453f + s_logdet + q);
    }
}

// ---------------------------------------------------------------------------
// Emission log-probs: emis[b,n,c] = bias_c + w_c.x - 0.5 * x^T P x
// 4 waves per block, one wave per (b,n).
// ---------------------------------------------------------------------------
__global__ __launch_bounds__(256) void k_emis(const float* __restrict__ feat,
                                              float* __restrict__ ws) {
    const int tid = threadIdx.x;
    const int w = tid >> 6, lane = tid & 63;
    const int flat = blockIdx.x * 4 + w;          // == b*N1 + n, 0..2043
    const int b = flat / N1, n = flat % N1;
    __shared__ float xs[4][64];

    const float x = feat[flat * 64 + lane];
    xs[w][lane] = x;
    __syncthreads();

    const float* __restrict__ P = ws + WS_P;
    float z = 0.0f;
    for (int dd = 0; dd < 64; ++dd) z += P[dd * 64 + lane] * xs[w][dd];

    float xz = x * z;
    for (int m = 32; m >= 1; m >>= 1) xz += __shfl_xor(xz, m);

    float val = BIG_NEG;
    if (lane < C1) {
        float s = ws[WS_BIAS + lane] - 0.5f * xz;
        const float* __restrict__ wT = ws + WS_W;
        for (int dd = 0; dd < 64; ++dd) s += wT[dd * 32 + lane] * xs[w][dd];
        val = s;
    }
    if (lane < C) ws[WS_EMIS + (b * N + n) * C + lane] = val;
}

// ---------------------------------------------------------------------------
// Padded cumsum over time per (b,c): chunked parallel scan, serial depth 32.
// One block per b; 512 threads = 16 chunks x 32 channels.
// ---------------------------------------------------------------------------
__global__ __launch_bounds__(512) void k_cumsum(float* __restrict__ ws) {
    const int b = blockIdx.x;
    const int tid = threadIdx.x;
    const int ch = tid >> 5, c = tid & 31;
    __shared__ float sh[512][32];

    const float* __restrict__ emis = ws + WS_EMIS + b * N * C;
    float* __restrict__ cs = ws + WS_CS + b * CSLEN * C;

    const int t0 = ch * 32;
    float acc = 0.0f;
#pragma unroll 4
    for (int i2 = 0; i2 < 32; ++i2) {
        acc += emis[(t0 + i2) * C + c];
        sh[t0 + i2][c] = acc;
    }
    __syncthreads();

    float off = 0.0f, tot = 0.0f;
#pragma unroll
    for (int ch2 = 0; ch2 < 16; ++ch2) {
        const float v = sh[ch2 * 32 + 31][c];
        if (ch2 < ch) off += v;
        tot += v;
    }

#pragma unroll 4
    for (int i2 = 0; i2 < 32; ++i2)
        cs[(t0 + i2 + 1) * C + c] = sh[t0 + i2][c] + off;

    if (ch == 0) cs[c] = 0.0f;
#pragma unroll
    for (int r = 0; r < 2; ++r) {
        const int i2 = N + 1 + ch * 2 + r;   // 513..544
        cs[i2 * C + c] = tot;
    }
}

// ---------------------------------------------------------------------------
// Main assembly: one block per (b,t); 256 threads; thread -> (cp, c0..c0+3);
// loop over k, fully-coalesced float4 stores.
// ---------------------------------------------------------------------------
__global__ __launch_bounds__(256) void k_main(const float* __restrict__ ws,
                                              float* __restrict__ out) {
    const int bid = blockIdx.x;
    const int b = bid / N1, t = bid % N1;
    const int tid = threadIdx.x;
    const int cp = tid >> 3;
    const int c0 = (tid & 7) << 2;

    __shared__ __align__(16) float slen[K * C];
    for (int idx = tid; idx < K * C; idx += 256) slen[idx] = ws[WS_LEN + idx];

    const float4 tr4 = *(const float4*)&ws[WS_TRANS + cp * 32 + c0];
    float4 in4 = {0.0f, 0.0f, 0.0f, 0.0f};
    if (t == 0) in4 = *(const float4*)&ws[WS_INIT + c0];

    const float* __restrict__ cs = ws + WS_CS + (b * CSLEN + t) * C;
    const float4 cst = *(const float4*)&cs[c0];

    float4 pre;
    pre.x = tr4.x + in4.x - cst.x;
    pre.y = tr4.y + in4.y - cst.y;
    pre.z = tr4.z + in4.z - cst.z;
    pre.w = tr4.w + in4.w - cst.w;

    const float emisN = (cp == C1) ? 0.0f : BIG_NEG;
    const int keos = N1 - t;  // matches k only when 1 <= keos <= 31

    const size_t obase = (size_t)bid * K * (C * C) + (size_t)(cp * 32 + c0);
    __syncthreads();

#pragma unroll 4
    for (int k = 0; k < K; ++k) {
        const float4 len4 = *(const float4*)&slen[k * 32 + c0];
        const float4 csk  = *(const float4*)&cs[k * C + c0];
        const float add = (k == keos) ? emisN : 0.0f;
        float4 o;
        o.x = pre.x + len4.x + csk.x + add;
        o.y = pre.y + len4.y + csk.y + add;
        o.z = pre.z + len4.z + csk.z + add;
        o.w = pre.w + len4.w + csk.w + add;
        *(float4*)&out[obase + (size_t)k * (C * C)] = o;
    }
}

// ---------------------------------------------------------------------------
extern "C" void kernel_launch(void* const* d_in, const int* in_sizes, int n_in,
                              void* d_out, int out_size, void* d_ws, size_t ws_size,
                              hipStream_t stream) {
    const float* feat = (const float*)d_in[0];
    const float* tl   = (const float*)d_in[1];
    const float* il   = (const float*)d_in[2];
    const float* plr  = (const float*)d_in[3];
    const float* gm   = (const float*)d_in[4];
    const float* gc   = (const float*)d_in[5];
    float* ws  = (float*)d_ws;
    float* out = (float*)d_out;

    hipLaunchKernelGGL(k_prep, dim3(1), dim3(1024), 0, stream, tl, il, plr, gc, gm, ws);
    hipLaunchKernelGGL(k_emis, dim3(B * N1 / 4), dim3(256), 0, stream, feat, ws);
    hipLaunchKernelGGL(k_cumsum, dim3(B), dim3(512), 0, stream, ws);
    hipLaunchKernelGGL(k_main, dim3(B * N1), dim3(256), 0, stream, ws, out);
}

// Round 4
// 106.603 us; speedup vs baseline: 3.4672x; 1.6222x over previous
//
#include <hip/hip_runtime.h>
#include <math.h>

#define BIG_NEG -1.0e9f

typedef float f4 __attribute__((ext_vector_type(4)));

// Problem constants (fixed by setup_inputs)
constexpr int B  = 4;
constexpr int N1 = 511;
constexpr int C1 = 31;
constexpr int K  = 32;
constexpr int N  = N1 + 1;        // 512
constexpr int C  = C1 + 1;        // 32

// Workspace layout (float offsets)
constexpr int WS_TRANS = 0;                    // [32][32]
constexpr int WS_INIT  = 1024;                 // [32]
constexpr int WS_LEN   = 1056;                 // [32][32]  (K x C)
constexpr int WS_P     = 2080;                 // [64][64]  precision matrix
constexpr int WS_W     = 6176;                 // [64][32]  wT[dd][c]
constexpr int WS_BIAS  = 8224;                 // [32]
constexpr int WS_EMIS  = 8256;                 // [B][N][C] = 65536

// ---------------------------------------------------------------------------
// Fused prep: single-barrier Gauss-Jordan (pivot-column pipelining +
// active-column masking) + small tables + wT + bias.
// ---------------------------------------------------------------------------
__global__ __launch_bounds__(512) void k_prep(const float* __restrict__ tl,
                                              const float* __restrict__ il,
                                              const float* __restrict__ plr,
                                              const float* __restrict__ cov,
                                              const float* __restrict__ means,
                                              float* __restrict__ ws) {
    __shared__ float M[64][132];   // [cov | I], row stride 132 (16B aligned)
    __shared__ float fc[2][64];    // double-buffered pivot column
    __shared__ float piv[64];
    __shared__ float rpiv_s[64];
    __shared__ float mu[C1][64];
    __shared__ float s_logdet;

    const int tid = threadIdx.x;
    const int ii = tid >> 3;       // row 0..63
    const int cg = tid & 7;        // owns float4 chunks {cg, cg+8, cg+16, cg+24}

    f4* Mrow = (f4*)&M[ii][0];

    // ---- load [cov | I] ----
    {
        Mrow[cg]     = *(const f4*)&cov[ii * 64 + 4 * cg];
        Mrow[cg + 8] = *(const f4*)&cov[ii * 64 + 4 * (cg + 8)];
        const int r0 = 4 * cg, r1 = 4 * (cg + 8);
        f4 e1 = {(ii == r0) ? 1.f : 0.f, (ii == r0 + 1) ? 1.f : 0.f,
                 (ii == r0 + 2) ? 1.f : 0.f, (ii == r0 + 3) ? 1.f : 0.f};
        f4 e2 = {(ii == r1) ? 1.f : 0.f, (ii == r1 + 1) ? 1.f : 0.f,
                 (ii == r1 + 2) ? 1.f : 0.f, (ii == r1 + 3) ? 1.f : 0.f};
        Mrow[cg + 16] = e1;
        Mrow[cg + 24] = e2;
    }
    if (cg == 0) fc[0][ii] = cov[ii * 64];  // pivot column 0
    for (int idx = tid; idx < C1 * 64; idx += 512)
        mu[idx >> 6][idx & 63] = means[idx];
    __syncthreads();

    // ---- Gauss-Jordan: ONE barrier per step ----
    for (int jj = 0; jj < 64; ++jj) {
        const int par = jj & 1;
        const float p = fc[par][jj];
        const float f = fc[par][ii] / p;
        if (tid == 0) piv[jj] = p;
        const f4* Mjj = (const f4*)&M[jj][0];
        const bool upd = (ii != jj);
#pragma unroll
        for (int h = 0; h < 4; ++h) {
            const int q = cg + 8 * h;
            const int k0 = 4 * q;
            // active cols at step jj: {jj..63} U {64..64+jj}
            const bool active = (k0 < 64) ? (k0 + 3 >= jj) : (k0 - 64 <= jj);
            if (!active) continue;
            f4 v = Mrow[q];
            if (upd) {
                v = v - f * Mjj[q];
                Mrow[q] = v;
            }
            // publish next pivot column (col jj+1) for next step
            if (jj < 63 && (unsigned)(jj + 1 - k0) < 4u) {
                const int d = jj + 1 - k0;
                fc[par ^ 1][ii] = (d == 0) ? v.x : (d == 1) ? v.y
                                 : (d == 2) ? v.z : v.w;
            }
        }
        __syncthreads();
    }

    // ---- logdet + reciprocal pivots ----
    if (tid == 0) {
        float s = 0.0f;
        for (int r = 0; r < 64; ++r) s += logf(piv[r]);
        s_logdet = s;
    }
    if (tid < 64) rpiv_s[tid] = 1.0f / piv[tid];
    __syncthreads();

    // ---- P = inv(cov) to global: P[ii][c] = M[ii][64+c] * rpiv[ii] ----
    {
        const float rp = rpiv_s[ii];
        f4 a = Mrow[16 + cg] * rp;
        f4 b = Mrow[24 + cg] * rp;
        *(f4*)&ws[WS_P + ii * 64 + 4 * cg] = a;
        *(f4*)&ws[WS_P + ii * 64 + 32 + 4 * cg] = b;
    }

    // ---- small tables ----
    for (int idx = tid; idx < 1024; idx += 512) {
        const int i = idx >> 5, j = idx & 31;
        ws[WS_TRANS + idx] = (i == C1) ? 0.0f : BIG_NEG;
        float lv;
        if (j < C1) {
            float lr = plr[j];
            lv = (float)i * lr - expf(lr) - lgammaf((float)i + 1.0f);
        } else {
            lv = (i == 1) ? 0.0f : BIG_NEG;
        }
        ws[WS_LEN + idx] = lv;
    }
    if (tid < B * C) {
        const int bb = tid >> 5, cc = tid & 31;
        ws[WS_EMIS + (bb * N + N1) * C + cc] = (cc == C1) ? 0.0f : BIG_NEG;
    }
    // trans columns: log_softmax over axis 0 with masked diagonal
    if (tid < C1) {
        const int jj = tid;
        float m = BIG_NEG;
        for (int r = 0; r < C1; ++r) {
            float v = (r == jj) ? BIG_NEG : tl[r * C1 + jj];
            m = fmaxf(m, v);
        }
        float s = 0.0f;
        for (int r = 0; r < C1; ++r) {
            float v = (r == jj) ? BIG_NEG : tl[r * C1 + jj];
            s += expf(v - m);
        }
        float lse = m + logf(s);
        for (int r = 0; r < C1; ++r) {
            float v = (r == jj) ? BIG_NEG : tl[r * C1 + jj];
            ws[WS_TRANS + r * 32 + jj] = v - lse;
        }
    }
    // init_a
    if (tid == 256) {
        float m = -1.0e30f;
        for (int cc = 0; cc < C1; ++cc) m = fmaxf(m, il[cc]);
        float s = 0.0f;
        for (int cc = 0; cc < C1; ++cc) s += expf(il[cc] - m);
        float lse = m + logf(s);
        for (int cc = 0; cc < C1; ++cc) ws[WS_INIT + cc] = il[cc] - lse;
        ws[WS_INIT + C1] = BIG_NEG;
    }

    // ---- wT[dd][c] = rpiv[dd] * (row_dd(Pscaled) . mu_c); bias via shfl ----
    {
        const int c = tid >> 4;    // 0..31
        const int l = tid & 15;
        if (c < C1) {
            float qacc = 0.0f;
#pragma unroll
            for (int h = 0; h < 4; ++h) {
                const int dd = l + 16 * h;
                float a = 0.0f;
                for (int e = 0; e < 64; ++e) a += M[dd][64 + e] * mu[c][e];
                a *= rpiv_s[dd];
                ws[WS_W + dd * 32 + c] = a;
                qacc += a * mu[c][dd];
            }
            for (int m2 = 8; m2 >= 1; m2 >>= 1) qacc += __shfl_xor(qacc, m2, 64);
            if (l == 0)
                ws[WS_BIAS + c] =
                    -0.5f * (64.0f * 1.8378770664093453f + s_logdet + qacc);
        }
    }
}

// ---------------------------------------------------------------------------
// Emission log-probs: emis[b,n,c] = bias_c + w_c.x - 0.5 * x^T P x
// 4 waves per block, one wave per (b,n).
// ---------------------------------------------------------------------------
__global__ __launch_bounds__(256) void k_emis(const float* __restrict__ feat,
                                              float* __restrict__ ws) {
    const int tid = threadIdx.x;
    const int w = tid >> 6, lane = tid & 63;
    const int flat = blockIdx.x * 4 + w;          // == b*N1 + n, 0..2043
    const int b = flat / N1, n = flat % N1;
    __shared__ float xs[4][64];

    const float x = feat[flat * 64 + lane];
    xs[w][lane] = x;
    __syncthreads();

    const float* __restrict__ P = ws + WS_P;
    float z = 0.0f;
    for (int dd = 0; dd < 64; ++dd) z += P[dd * 64 + lane] * xs[w][dd];

    float xz = x * z;
    for (int m = 32; m >= 1; m >>= 1) xz += __shfl_xor(xz, m);

    float val = BIG_NEG;
    if (lane < C1) {
        float s = ws[WS_BIAS + lane] - 0.5f * xz;
        const float* __restrict__ wT = ws + WS_W;
        for (int dd = 0; dd < 64; ++dd) s += wT[dd * 32 + lane] * xs[w][dd];
        val = s;
    }
    if (lane < C) ws[WS_EMIS + (b * N + n) * C + lane] = val;
}

// ---------------------------------------------------------------------------
// Main assembly (fused local window-scan): one block per (b,t); loads emis
// rows t..t+31 into LDS, per-column prefix scan, then 32 coalesced f4 stores
// per thread-row along k. No global cumsum array, no k_cumsum kernel.
// ---------------------------------------------------------------------------
__global__ __launch_bounds__(256) void k_main(const float* __restrict__ ws,
                                              float* __restrict__ out) {
    const int bid = blockIdx.x;
    const int b = bid / N1, t = bid % N1;
    const int tid = threadIdx.x;
    __shared__ float sh[32][32];

    // load emis rows t..t+31 (zero past row N-1)
    {
        const int row = tid >> 3;            // 0..31
        const int c4 = (tid & 7) << 2;       // 0,4,...,28
        f4 v = {0.f, 0.f, 0.f, 0.f};
        if (t + row < N)
            v = *(const f4*)&ws[WS_EMIS + (b * N + t + row) * C + c4];
        *(f4*)&sh[row][c4] = v;
    }
    __syncthreads();

    // inclusive prefix scan along rows, per column (serial by 32 lanes;
    // hidden by the other co-resident blocks' store traffic)
    if (tid < 32) {
        float acc = 0.0f;
#pragma unroll
        for (int i = 0; i < 32; ++i) {
            acc += sh[i][tid];
            sh[i][tid] = acc;
        }
    }

    const int cp = tid >> 3;
    const int c0 = (tid & 7) << 2;
    f4 pre = *(const f4*)&ws[WS_TRANS + cp * 32 + c0];
    if (t == 0) {
        f4 in4 = *(const f4*)&ws[WS_INIT + c0];
        pre = pre + in4;
    }
    const float emisN = (cp == C1) ? 0.0f : BIG_NEG;
    const int keos = N1 - t;  // matches k only when 1 <= keos <= 31
    const size_t obase = (size_t)bid * (K * C * C) + (size_t)(cp * 32 + c0);
    __syncthreads();

#pragma unroll 4
    for (int k = 0; k < K; ++k) {
        f4 len4 = *(const f4*)&ws[WS_LEN + k * 32 + c0];
        f4 w4 = {0.f, 0.f, 0.f, 0.f};
        if (k > 0) w4 = *(const f4*)&sh[k - 1][c0];
        f4 o = pre + len4 + w4;
        if (k == keos) o = o + emisN;
        __builtin_nontemporal_store(o, (f4*)&out[obase + (size_t)k * (C * C)]);
    }
}

// ---------------------------------------------------------------------------
extern "C" void kernel_launch(void* const* d_in, const int* in_sizes, int n_in,
                              void* d_out, int out_size, void* d_ws, size_t ws_size,
                              hipStream_t stream) {
    const float* feat = (const float*)d_in[0];
    const float* tl   = (const float*)d_in[1];
    const float* il   = (const float*)d_in[2];
    const float* plr  = (const float*)d_in[3];
    const float* gm   = (const float*)d_in[4];
    const float* gc   = (const float*)d_in[5];
    float* ws  = (float*)d_ws;
    float* out = (float*)d_out;

    hipLaunchKernelGGL(k_prep, dim3(1), dim3(512), 0, stream, tl, il, plr, gc, gm, ws);
    hipLaunchKernelGGL(k_emis, dim3(B * N1 / 4), dim3(256), 0, stream, feat, ws);
    hipLaunchKernelGGL(k_main, dim3(B * N1), dim3(256), 0, stream, ws, out);
}

// Round 5
// 106.516 us; speedup vs baseline: 3.4700x; 1.0008x over previous
//
#include <hip/hip_runtime.h>
#include <math.h>

#define BIG_NEG -1.0e9f

typedef float f4 __attribute__((ext_vector_type(4)));

// Problem constants (fixed by setup_inputs)
constexpr int B  = 4;
constexpr int N1 = 511;
constexpr int C1 = 31;
constexpr int K  = 32;
constexpr int N  = N1 + 1;        // 512
constexpr int C  = C1 + 1;        // 32

// Workspace layout (float offsets)
constexpr int WS_TRANS = 0;                    // [32][32]
constexpr int WS_INIT  = 1024;                 // [32]
constexpr int WS_LEN   = 1056;                 // [32][32]  (K x C)
constexpr int WS_P     = 2080;                 // [64][64]  precision matrix
constexpr int WS_W     = 6176;                 // [64][32]  wT[dd][c]
constexpr int WS_BIAS  = 8224;                 // [32]
constexpr int WS_EMIS  = 8256;                 // [B][N][C] = 65536

// ---------------------------------------------------------------------------
// Fused prep: single-barrier Gauss-Jordan (pivot-column pipelining +
// active-column masking) + small tables + wT + bias.
// ---------------------------------------------------------------------------
__global__ __launch_bounds__(512) void k_prep(const float* __restrict__ tl,
                                              const float* __restrict__ il,
                                              const float* __restrict__ plr,
                                              const float* __restrict__ cov,
                                              const float* __restrict__ means,
                                              float* __restrict__ ws) {
    __shared__ float M[64][132];   // [cov | I], row stride 132 (16B aligned)
    __shared__ float fc[2][64];    // double-buffered pivot column
    __shared__ float piv[64];
    __shared__ float rpiv_s[64];
    __shared__ float mu[C1][64];
    __shared__ float s_logdet;

    const int tid = threadIdx.x;
    const int ii = tid >> 3;       // row 0..63
    const int cg = tid & 7;        // owns float4 chunks {cg, cg+8, cg+16, cg+24}

    f4* Mrow = (f4*)&M[ii][0];

    // ---- load [cov | I] ----
    {
        Mrow[cg]     = *(const f4*)&cov[ii * 64 + 4 * cg];
        Mrow[cg + 8] = *(const f4*)&cov[ii * 64 + 4 * (cg + 8)];
        const int r0 = 4 * cg, r1 = 4 * (cg + 8);
        f4 e1 = {(ii == r0) ? 1.f : 0.f, (ii == r0 + 1) ? 1.f : 0.f,
                 (ii == r0 + 2) ? 1.f : 0.f, (ii == r0 + 3) ? 1.f : 0.f};
        f4 e2 = {(ii == r1) ? 1.f : 0.f, (ii == r1 + 1) ? 1.f : 0.f,
                 (ii == r1 + 2) ? 1.f : 0.f, (ii == r1 + 3) ? 1.f : 0.f};
        Mrow[cg + 16] = e1;
        Mrow[cg + 24] = e2;
    }
    if (cg == 0) fc[0][ii] = cov[ii * 64];  // pivot column 0
    for (int idx = tid; idx < C1 * 64; idx += 512)
        mu[idx >> 6][idx & 63] = means[idx];
    __syncthreads();

    // ---- Gauss-Jordan: ONE barrier per step ----
    for (int jj = 0; jj < 64; ++jj) {
        const int par = jj & 1;
        const float p = fc[par][jj];
        const float f = fc[par][ii] / p;
        if (tid == 0) piv[jj] = p;
        const f4* Mjj = (const f4*)&M[jj][0];
        const bool upd = (ii != jj);
#pragma unroll
        for (int h = 0; h < 4; ++h) {
            const int q = cg + 8 * h;
            const int k0 = 4 * q;
            // active cols at step jj: {jj..63} U {64..64+jj}
            const bool active = (k0 < 64) ? (k0 + 3 >= jj) : (k0 - 64 <= jj);
            if (!active) continue;
            f4 v = Mrow[q];
            if (upd) {
                v = v - f * Mjj[q];
                Mrow[q] = v;
            }
            // publish next pivot column (col jj+1) for next step
            if (jj < 63 && (unsigned)(jj + 1 - k0) < 4u) {
                const int d = jj + 1 - k0;
                fc[par ^ 1][ii] = (d == 0) ? v.x : (d == 1) ? v.y
                                 : (d == 2) ? v.z : v.w;
            }
        }
        __syncthreads();
    }

    // ---- logdet + reciprocal pivots ----
    if (tid == 0) {
        float s = 0.0f;
        for (int r = 0; r < 64; ++r) s += logf(piv[r]);
        s_logdet = s;
    }
    if (tid < 64) rpiv_s[tid] = 1.0f / piv[tid];
    __syncthreads();

    // ---- P = inv(cov) to global: P[ii][c] = M[ii][64+c] * rpiv[ii] ----
    {
        const float rp = rpiv_s[ii];
        f4 a = Mrow[16 + cg] * rp;
        f4 b = Mrow[24 + cg] * rp;
        *(f4*)&ws[WS_P + ii * 64 + 4 * cg] = a;
        *(f4*)&ws[WS_P + ii * 64 + 32 + 4 * cg] = b;
    }

    // ---- small tables ----
    for (int idx = tid; idx < 1024; idx += 512) {
        const int i = idx >> 5, j = idx & 31;
        ws[WS_TRANS + idx] = (i == C1) ? 0.0f : BIG_NEG;
        float lv;
        if (j < C1) {
            float lr = plr[j];
            lv = (float)i * lr - expf(lr) - lgammaf((float)i + 1.0f);
        } else {
            lv = (i == 1) ? 0.0f : BIG_NEG;
        }
        ws[WS_LEN + idx] = lv;
    }
    if (tid < B * C) {
        const int bb = tid >> 5, cc = tid & 31;
        ws[WS_EMIS + (bb * N + N1) * C + cc] = (cc == C1) ? 0.0f : BIG_NEG;
    }
    // trans columns: log_softmax over axis 0 with masked diagonal
    if (tid < C1) {
        const int jj = tid;
        float m = BIG_NEG;
        for (int r = 0; r < C1; ++r) {
            float v = (r == jj) ? BIG_NEG : tl[r * C1 + jj];
            m = fmaxf(m, v);
        }
        float s = 0.0f;
        for (int r = 0; r < C1; ++r) {
            float v = (r == jj) ? BIG_NEG : tl[r * C1 + jj];
            s += expf(v - m);
        }
        float lse = m + logf(s);
        for (int r = 0; r < C1; ++r) {
            float v = (r == jj) ? BIG_NEG : tl[r * C1 + jj];
            ws[WS_TRANS + r * 32 + jj] = v - lse;
        }
    }
    // init_a
    if (tid == 256) {
        float m = -1.0e30f;
        for (int cc = 0; cc < C1; ++cc) m = fmaxf(m, il[cc]);
        float s = 0.0f;
        for (int cc = 0; cc < C1; ++cc) s += expf(il[cc] - m);
        float lse = m + logf(s);
        for (int cc = 0; cc < C1; ++cc) ws[WS_INIT + cc] = il[cc] - lse;
        ws[WS_INIT + C1] = BIG_NEG;
    }

    // ---- wT[dd][c] = rpiv[dd] * (row_dd(Pscaled) . mu_c); bias via shfl ----
    {
        const int c = tid >> 4;    // 0..31
        const int l = tid & 15;
        if (c < C1) {
            float qacc = 0.0f;
#pragma unroll
            for (int h = 0; h < 4; ++h) {
                const int dd = l + 16 * h;
                float a = 0.0f;
                for (int e = 0; e < 64; ++e) a += M[dd][64 + e] * mu[c][e];
                a *= rpiv_s[dd];
                ws[WS_W + dd * 32 + c] = a;
                qacc += a * mu[c][dd];
            }
            for (int m2 = 8; m2 >= 1; m2 >>= 1) qacc += __shfl_xor(qacc, m2, 64);
            if (l == 0)
                ws[WS_BIAS + c] =
                    -0.5f * (64.0f * 1.8378770664093453f + s_logdet + qacc);
        }
    }
}

// ---------------------------------------------------------------------------
// Emission log-probs: emis[b,n,c] = bias_c + w_c.x - 0.5 * x^T P x
// 4 waves per block, one wave per (b,n).
// ---------------------------------------------------------------------------
__global__ __launch_bounds__(256) void k_emis(const float* __restrict__ feat,
                                              float* __restrict__ ws) {
    const int tid = threadIdx.x;
    const int w = tid >> 6, lane = tid & 63;
    const int flat = blockIdx.x * 4 + w;          // == b*N1 + n, 0..2043
    const int b = flat / N1, n = flat % N1;
    __shared__ float xs[4][64];

    const float x = feat[flat * 64 + lane];
    xs[w][lane] = x;
    __syncthreads();

    const float* __restrict__ P = ws + WS_P;
    float z = 0.0f;
    for (int dd = 0; dd < 64; ++dd) z += P[dd * 64 + lane] * xs[w][dd];

    float xz = x * z;
    for (int m = 32; m >= 1; m >>= 1) xz += __shfl_xor(xz, m);

    float val = BIG_NEG;
    if (lane < C1) {
        float s = ws[WS_BIAS + lane] - 0.5f * xz;
        const float* __restrict__ wT = ws + WS_W;
        for (int dd = 0; dd < 64; ++dd) s += wT[dd * 32 + lane] * xs[w][dd];
        val = s;
    }
    if (lane < C) ws[WS_EMIS + (b * N + n) * C + lane] = val;
}

// ---------------------------------------------------------------------------
// Main assembly (fused local window-scan): one block per (b,t); loads emis
// rows t..t+31 into LDS, per-column prefix scan, then 32 coalesced f4 stores
// per thread-row along k. No global cumsum array, no k_cumsum kernel.
// ---------------------------------------------------------------------------
__global__ __launch_bounds__(256) void k_main(const float* __restrict__ ws,
                                              float* __restrict__ out) {
    const int bid = blockIdx.x;
    const int b = bid / N1, t = bid % N1;
    const int tid = threadIdx.x;
    __shared__ float sh[32][32];

    // load emis rows t..t+31 (zero past row N-1)
    {
        const int row = tid >> 3;            // 0..31
        const int c4 = (tid & 7) << 2;       // 0,4,...,28
        f4 v = {0.f, 0.f, 0.f, 0.f};
        if (t + row < N)
            v = *(const f4*)&ws[WS_EMIS + (b * N + t + row) * C + c4];
        *(f4*)&sh[row][c4] = v;
    }
    __syncthreads();

    // inclusive prefix scan along rows, per column (serial by 32 lanes;
    // hidden by the other co-resident blocks' store traffic)
    if (tid < 32) {
        float acc = 0.0f;
#pragma unroll
        for (int i = 0; i < 32; ++i) {
            acc += sh[i][tid];
            sh[i][tid] = acc;
        }
    }

    const int cp = tid >> 3;
    const int c0 = (tid & 7) << 2;
    f4 pre = *(const f4*)&ws[WS_TRANS + cp * 32 + c0];
    if (t == 0) {
        f4 in4 = *(const f4*)&ws[WS_INIT + c0];
        pre = pre + in4;
    }
    const float emisN = (cp == C1) ? 0.0f : BIG_NEG;
    const int keos = N1 - t;  // matches k only when 1 <= keos <= 31
    const size_t obase = (size_t)bid * (K * C * C) + (size_t)(cp * 32 + c0);
    __syncthreads();

#pragma unroll 4
    for (int k = 0; k < K; ++k) {
        f4 len4 = *(const f4*)&ws[WS_LEN + k * 32 + c0];
        f4 w4 = {0.f, 0.f, 0.f, 0.f};
        if (k > 0) w4 = *(const f4*)&sh[k - 1][c0];
        f4 o = pre + len4 + w4;
        if (k == keos) o = o + emisN;
        __builtin_nontemporal_store(o, (f4*)&out[obase + (size_t)k * (C * C)]);
    }
}

// ---------------------------------------------------------------------------
extern "C" void kernel_launch(void* const* d_in, const int* in_sizes, int n_in,
                              void* d_out, int out_size, void* d_ws, size_t ws_size,
                              hipStream_t stream) {
    const float* feat = (const float*)d_in[0];
    const float* tl   = (const float*)d_in[1];
    const float* il   = (const float*)d_in[2];
    const float* plr  = (const float*)d_in[3];
    const float* gm   = (const float*)d_in[4];
    const float* gc   = (const float*)d_in[5];
    float* ws  = (float*)d_ws;
    float* out = (float*)d_out;

    hipLaunchKernelGGL(k_prep, dim3(1), dim3(512), 0, stream, tl, il, plr, gc, gm, ws);
    hipLaunchKernelGGL(k_emis, dim3(B * N1 / 4), dim3(256), 0, stream, feat, ws);
    hipLaunchKernelGGL(k_main, dim3(B * N1), dim3(256), 0, stream, ws, out);
}